// Round 2
// baseline (59392.133 us; speedup 1.0000x reference)
//
#include <hip/hip_runtime.h>
#include <hip/hip_bf16.h>

typedef __hip_bfloat16 bf16;
typedef _Float16 half2v __attribute__((ext_vector_type(2)));

#define T_LEN 4096
#define D_IN  128
#define H_DIM 512
#define E_DIM 256
#define WNUM  4
#define G3    1536
#define NBLK  64   // sequential workgroups (1 per CU => all co-resident)

// ---- workspace layout (bytes) ----
#define OFF_HFLAG  0ull
#define OFF_CWFLAG 4096ull
#define OFF_MODE   8192ull
#define OFF_FMODE  8196ull
#define OFF_A      16384ull                                   // bf16 [4096][1536]
#define OFF_AXA    (OFF_A   + 4096ull*1536ull*2ull)           // bf16 [4096][512]
#define OFF_GW0    (OFF_AXA + 4096ull*512ull*2ull)            // bf16 [16384][1536]
#define OFF_HBUF   (OFF_GW0 + 16384ull*1536ull*2ull)          // f32  [4096][512]
#define OFF_CBUF   (OFF_HBUF + 4096ull*512ull*4ull)           // f32  [4096][512]
#define OFF_CW     (OFF_CBUF + 4096ull*512ull*4ull)           // f32  [2][4][512]
// total ~84 MB

__device__ __forceinline__ float bf2f(bf16 h) {
  unsigned short u = __builtin_bit_cast(unsigned short, h);
  unsigned int i = ((unsigned int)u) << 16;
  return __builtin_bit_cast(float, i);
}
__device__ __forceinline__ unsigned short f2bfbits(float f) {
  return __builtin_bit_cast(unsigned short, __float2bfloat16(f));
}
__device__ __forceinline__ unsigned int packbf(float a, float b) {
  return (unsigned int)f2bfbits(a) | ((unsigned int)f2bfbits(b) << 16);
}
__device__ __forceinline__ float sigm(float x) { return 1.f / (1.f + __expf(-x)); }
__device__ __forceinline__ float tanhfast(float x) { return 1.f - 2.f / (__expf(2.f * x) + 1.f); }

#if __has_builtin(__builtin_amdgcn_fdot2)
__device__ __forceinline__ float fdot2(half2v a, half2v b, float c) {
  return __builtin_amdgcn_fdot2(a, b, c, false);
}
#else
__device__ __forceinline__ float fdot2(half2v a, half2v b, float c) {
  return c + (float)a.x * (float)b.x + (float)a.y * (float)b.y;
}
#endif

__device__ __forceinline__ half2v make2(float a, float b) {
  half2v r; r.x = (_Float16)a; r.y = (_Float16)b; return r;
}

// ---- dtype-adaptive loads: fm==1 -> float32, fm==0 -> bf16 ----
__device__ __forceinline__ float ldf(const void* p, size_t i, int fm) {
  return fm ? ((const float*)p)[i] : bf2f(((const bf16*)p)[i]);
}
__device__ __forceinline__ void ld8(const void* p, size_t i, int fm, float* o) {
  if (fm) {
    const float* q = (const float*)p + i;   // i % 4 == 0 at all call sites
    float4 a = *(const float4*)q, b2 = *(const float4*)(q + 4);
    o[0]=a.x; o[1]=a.y; o[2]=a.z; o[3]=a.w; o[4]=b2.x; o[5]=b2.y; o[6]=b2.z; o[7]=b2.w;
  } else {
    uint4 raw = *(const uint4*)((const bf16*)p + i);  // i % 8 == 0 at call sites
    unsigned int u[4] = {raw.x, raw.y, raw.z, raw.w};
#pragma unroll
    for (int j = 0; j < 4; ++j) {
      o[2*j]   = __builtin_bit_cast(float, u[j] << 16);
      o[2*j+1] = __builtin_bit_cast(float, u[j] & 0xffff0000u);
    }
  }
}
__device__ __forceinline__ void ld4(const void* p, size_t i, int fm, float* o) {
  if (fm) {
    float4 a = *(const float4*)((const float*)p + i);  // i % 4 == 0
    o[0]=a.x; o[1]=a.y; o[2]=a.z; o[3]=a.w;
  } else {
    uint2 raw = *(const uint2*)((const bf16*)p + i);
    o[0] = __builtin_bit_cast(float, raw.x << 16);
    o[1] = __builtin_bit_cast(float, raw.x & 0xffff0000u);
    o[2] = __builtin_bit_cast(float, raw.y << 16);
    o[3] = __builtin_bit_cast(float, raw.y & 0xffff0000u);
  }
}
// mask read: mode 0=int32, 1=byte, 2=bf16 halfword, 3=f32 dword
__device__ __forceinline__ bool readmask(const void* p, int idx, int mode) {
  switch (mode) {
    case 0:  return ((const int*)p)[idx] != 0;
    case 1:  return ((const unsigned char*)p)[idx] != 0;
    case 2:  return ((const unsigned short*)p)[idx] != 0;
    default: return ((const unsigned int*)p)[idx] != 0;
  }
}

// ============ init: zero flags, detect mask dtype + float width ============
__global__ void k_init(const void* __restrict__ mask_p, const void* __restrict__ h0_p,
                       unsigned char* __restrict__ ws) {
  int tid = threadIdx.x;
  __shared__ int s_b1, s_bf, s_f32, s_votes;
  if (tid == 0) { s_b1 = 0; s_bf = 0; s_f32 = 0; s_votes = 0; }
  __syncthreads();
  int b1 = 0, bfh = 0, f32h = 0;
  const unsigned int* dv = (const unsigned int*)mask_p;
  for (int i = tid; i < 4096; i += 256) {   // first 16KB: safe for every candidate dtype
    unsigned int d = dv[i];
    if (((d >> 8) & 0xFFu) == 1u || ((d >> 16) & 0xFFu) == 1u || ((d >> 24) & 0xFFu) == 1u) b1 = 1;
    if ((d & 0xFFFFu) == 0x3F80u) bfh = 1;       // even halfword == bf16(1.0)
    if (d == 0x3F800000u) f32h = 1;              // dword == f32(1.0)
  }
  if (b1)  atomicOr(&s_b1, 1);
  if (bfh) atomicOr(&s_bf, 1);
  if (f32h) atomicOr(&s_f32, 1);
  if (tid < 128) {                               // h0 ~ N(0,1): f32 exponent voting
    unsigned int d = ((const unsigned int*)h0_p)[tid];  // 512B, safe for bf16(1KB)/f32(2KB)
    int e = (int)((d >> 23) & 0xFF);
    if (e >= 100 && e <= 140) atomicAdd(&s_votes, 1);
  }
  __syncthreads();
  int* flags = (int*)ws;
  for (int i = tid; i < 2048; i += 256) flags[i] = 0;   // Hflag + cwFlag
  if (tid == 0) {
    int mode = s_b1 ? 1 : (s_bf ? 2 : (s_f32 ? 3 : 0));
    *(int*)(ws + OFF_MODE)  = mode;
    *(int*)(ws + OFF_FMODE) = (s_votes >= 64) ? 1 : 0;
  }
}

// ============ A = x@W + b ; Axa = x@Wa + ba  (bf16 out) ============
__global__ __launch_bounds__(256) void k_xgemm(
    const void* __restrict__ x, const void* __restrict__ W, const void* __restrict__ b,
    const void* __restrict__ Wa, const void* __restrict__ ba, unsigned char* __restrict__ ws) {
  const int fm = *(const int*)(ws + OFF_FMODE);
  bf16* A   = (bf16*)(ws + OFF_A);
  bf16* Axa = (bf16*)(ws + OFF_AXA);
  const int tid = threadIdx.x;
  const int t0 = blockIdx.x * 8;
  __shared__ float sx[8][128];
  {
    int flat = tid * 4, r = flat >> 7, k = flat & 127;
    ld4(x, (size_t)(t0 + r) * D_IN + k, fm, &sx[r][k]);
  }
  __syncthreads();
  const bool isA = (tid < 192);
  const int c0 = isA ? tid * 8 : (tid - 192) * 8;
  const void* M = isA ? W : Wa;
  const int ldm = isA ? G3 : H_DIM;
  float acc[8][8];
#pragma unroll
  for (int r = 0; r < 8; ++r)
#pragma unroll
    for (int c = 0; c < 8; ++c) acc[r][c] = 0.f;
  for (int k = 0; k < D_IN; ++k) {
    float wv[8];
    ld8(M, (size_t)k * ldm + c0, fm, wv);
#pragma unroll
    for (int r = 0; r < 8; ++r) {
      float xv = sx[r][k];
#pragma unroll
      for (int c = 0; c < 8; ++c) acc[r][c] += xv * wv[c];
    }
  }
  float bias[8];
  ld8(isA ? b : ba, c0, fm, bias);
#pragma unroll
  for (int r = 0; r < 8; ++r) {
    uint4 o;
    o.x = packbf(acc[r][0] + bias[0], acc[r][1] + bias[1]);
    o.y = packbf(acc[r][2] + bias[2], acc[r][3] + bias[3]);
    o.z = packbf(acc[r][4] + bias[4], acc[r][5] + bias[5]);
    o.w = packbf(acc[r][6] + bias[6], acc[r][7] + bias[7]);
    if (isA) *(uint4*)(A + (size_t)(t0 + r) * G3 + c0) = o;
    else     *(uint4*)(Axa + (size_t)(t0 + r) * H_DIM + c0) = o;
  }
}

// ============ GW0[row] = emb[wid]@Ww + bw  (masked rows only, bf16 out) ============
__global__ __launch_bounds__(256) void k_wgemm(
    const int* __restrict__ wids, const void* __restrict__ wmask,
    const void* __restrict__ emb, const void* __restrict__ Ww, const void* __restrict__ bw,
    unsigned char* __restrict__ ws) {
  const int mode = *(const int*)(ws + OFF_MODE);
  const int fm   = *(const int*)(ws + OFF_FMODE);
  bf16* GW0 = (bf16*)(ws + OFF_GW0);
  const int tid = threadIdx.x;
  const int r0 = blockIdx.x * 8;
  bool m[8]; bool any = false;
#pragma unroll
  for (int r = 0; r < 8; ++r) {
    bool mm = readmask(wmask, r0 + r, mode);
    m[r] = mm; any |= mm;
  }
  if (!any) return;
  __shared__ float se[8][E_DIM];
#pragma unroll
  for (int r = 0; r < 8; ++r)
    if (m[r]) {
      int wid = wids[r0 + r];
      se[r][tid] = ldf(emb, (size_t)wid * E_DIM + tid, fm);
    }
  __syncthreads();
  if (tid < 192) {
    const int c0 = tid * 8;
    float acc[8][8];
#pragma unroll
    for (int r = 0; r < 8; ++r)
#pragma unroll
      for (int c = 0; c < 8; ++c) acc[r][c] = 0.f;
    for (int k = 0; k < E_DIM; ++k) {
      float wv[8];
      ld8(Ww, (size_t)k * G3 + c0, fm, wv);
#pragma unroll
      for (int r = 0; r < 8; ++r)
        if (m[r]) {
          float xv = se[r][k];
#pragma unroll
          for (int c = 0; c < 8; ++c) acc[r][c] += xv * wv[c];
        }
    }
    float bias[8];
    ld8(bw, c0, fm, bias);
#pragma unroll
    for (int r = 0; r < 8; ++r)
      if (m[r]) {
        uint4 o;
        o.x = packbf(acc[r][0] + bias[0], acc[r][1] + bias[1]);
        o.y = packbf(acc[r][2] + bias[2], acc[r][3] + bias[3]);
        o.z = packbf(acc[r][4] + bias[4], acc[r][5] + bias[5]);
        o.w = packbf(acc[r][6] + bias[6], acc[r][7] + bias[7]);
        *(uint4*)(GW0 + (size_t)(r0 + r) * G3 + c0) = o;
      }
  }
}

// ---- per-wave dot pass: lane(cg=lane>>3, rg=lane&7); lane rows {64m+8rg..+7} ----
#define PASS(slotptr, wt, accvar) do {                                  \
    float _acc = 0.f;                                                   \
    const _Float16* _vp = (slotptr) + 8 * rg;                           \
    _Pragma("unroll")                                                   \
    for (int _m = 0; _m < 8; ++_m) {                                    \
      float4 _raw = *(const float4*)(_vp + 64 * _m);                    \
      half2v _h0 = __builtin_bit_cast(half2v, _raw.x);                  \
      half2v _h1 = __builtin_bit_cast(half2v, _raw.y);                  \
      half2v _h2 = __builtin_bit_cast(half2v, _raw.z);                  \
      half2v _h3 = __builtin_bit_cast(half2v, _raw.w);                  \
      _acc = fdot2(_h0, wt[_m * 4 + 0], _acc);                          \
      _acc = fdot2(_h1, wt[_m * 4 + 1], _acc);                          \
      _acc = fdot2(_h2, wt[_m * 4 + 2], _acc);                          \
      _acc = fdot2(_h3, wt[_m * 4 + 3], _acc);                          \
    }                                                                   \
    accvar = _acc;                                                      \
  } while (0)

// ============ sequential lattice recurrence: 64 persistent WGs ============
__global__ __launch_bounds__(256, 1) void k_seq(
    const int* __restrict__ wstarts, const void* __restrict__ wmask,
    const void* __restrict__ h0_p, const void* __restrict__ c0_p,
    const void* __restrict__ U, const void* __restrict__ Uw, const void* __restrict__ Ua,
    unsigned char* __restrict__ ws, void* __restrict__ outp) {
  const int tid = threadIdx.x;
  const int blk = blockIdx.x;
  const int wv = tid >> 6;
  const int lane = tid & 63;
  const int cg = lane >> 3;
  const int rg = lane & 7;
  const int kbase = blk * 8 + wv * 2;  // global k for kl=0 of this wave

  const int mode = *(const int*)(ws + OFF_MODE);
  const int fm   = *(const int*)(ws + OFF_FMODE);
  const bf16* A   = (const bf16*)(ws + OFF_A);
  const bf16* Axa = (const bf16*)(ws + OFF_AXA);
  const bf16* GW0 = (const bf16*)(ws + OFF_GW0);
  float* Hbuf  = (float*)(ws + OFF_HBUF);
  float* Cbuf  = (float*)(ws + OFF_CBUF);
  float* cwBuf = (float*)(ws + OFF_CW);
  int* Hflag  = (int*)(ws + OFF_HFLAG);
  int* cwFlag = (int*)(ws + OFF_CWFLAG);

  __shared__ __align__(16) _Float16 hring[8][520];    // full h ring (f16, +8 pad)
  __shared__ __align__(16) _Float16 cwlds[WNUM][520]; // full c_w per word
  __shared__ float cring[8][8];                       // own 8 c-columns ring
  __shared__ float scr[4][8];                         // per-wave reduce scratch
  __shared__ float cwown[4][WNUM][2];                 // own c_w values per wave

  // ---- zero-init all LDS (defense: any read path stays finite) ----
  {
    _Float16* hz = &hring[0][0];
    for (int i = tid; i < 8 * 520; i += 256) hz[i] = (_Float16)0.f;
    _Float16* cz = &cwlds[0][0];
    for (int i = tid; i < WNUM * 520; i += 256) cz[i] = (_Float16)0.f;
    float* cr = &cring[0][0];
    for (int i = tid; i < 64; i += 256) cr[i] = 0.f;
    if (tid < 32) (&scr[0][0])[tid] = 0.f;
    if (tid < 32) (&cwown[0][0][0])[tid] = 0.f;
  }

  // ---- persistent weights in VGPRs (f16 pairs) ----
  half2v wU[32], wUw[32], wUa[32];
  {
    const int gate = cg >> 1;
    const int klw = cg & 1;
    const int colU = gate * H_DIM + (kbase + klw);  // valid when cg<6
    const int colA = kbase + cg;                    // valid when cg<2
#pragma unroll
    for (int mq = 0; mq < 32; ++mq) {
      int mm = mq >> 2, q = mq & 3;
      int r = 64 * mm + 8 * rg + 2 * q;
      float u0 = 0, u1 = 0, v0 = 0, v1 = 0, a0 = 0, a1 = 0;
      if (cg < 6) {
        u0 = ldf(U, (size_t)r * G3 + colU, fm);  u1 = ldf(U, (size_t)(r + 1) * G3 + colU, fm);
        v0 = ldf(Uw, (size_t)r * G3 + colU, fm); v1 = ldf(Uw, (size_t)(r + 1) * G3 + colU, fm);
      }
      if (cg < 2) {
        a0 = ldf(Ua, (size_t)r * H_DIM + colA, fm); a1 = ldf(Ua, (size_t)(r + 1) * H_DIM + colA, fm);
      }
      wU[mq] = make2(u0, u1); wUw[mq] = make2(v0, v1); wUa[mq] = make2(a0, a1);
    }
  }
  __syncthreads();

  // ---- preload ring slot 7 with h0/c0 (the "t-1" state of step 0) ----
  {
    int i = tid * 2;
    hring[7][i]     = (_Float16)ldf(h0_p, i, fm);
    hring[7][i + 1] = (_Float16)ldf(h0_p, i + 1, fm);
    if (tid < 8) cring[7][tid] = ldf(c0_p, blk * 8 + tid, fm);
  }
  __syncthreads();

  for (int t = 0; t < T_LEN; ++t) {
    // ---- word metadata (uniform broadcast loads) ----
    int st[WNUM]; bool val[WNUM]; bool anyw = false;
#pragma unroll
    for (int w = 0; w < WNUM; ++w) {
      st[w] = wstarts[t * WNUM + w];
      bool mmk = readmask(wmask, t * WNUM + w, mode);
      val[w] = mmk; anyw |= mmk;
    }
    // ---- prefetch per-wave scalar terms (LLC, issued early) ----
    float gwx[WNUM][6], aT[6], axaT[2];
#pragma unroll
    for (int w = 0; w < WNUM; ++w)
      if (val[w]) {
#pragma unroll
        for (int g3 = 0; g3 < 3; ++g3)
#pragma unroll
          for (int kl = 0; kl < 2; ++kl)
            gwx[w][g3 * 2 + kl] =
                bf2f(GW0[(size_t)(t * WNUM + w) * G3 + g3 * H_DIM + kbase + kl]);
      }
#pragma unroll
    for (int g3 = 0; g3 < 3; ++g3)
#pragma unroll
      for (int kl = 0; kl < 2; ++kl)
        aT[g3 * 2 + kl] = bf2f(A[(size_t)t * G3 + g3 * H_DIM + kbase + kl]);
#pragma unroll
    for (int kl = 0; kl < 2; ++kl)
      axaT[kl] = bf2f(Axa[(size_t)t * H_DIM + kbase + kl]);

    // ---- early Uw passes (word start <= t-2: ring state already present) ----
    float accw[WNUM] = {0.f, 0.f, 0.f, 0.f};
#pragma unroll
    for (int w = 0; w < WNUM; ++w)
      if (val[w] && st[w] <= t - 2) PASS(&hring[st[w] & 7][0], wUw, accw[w]);

    // ---- wait for h[t-1], fill ring ----
    if (t > 0) {
      if (tid < 64) {
        int* fp = Hflag + tid * 16;
        while (__hip_atomic_load(fp, __ATOMIC_RELAXED, __HIP_MEMORY_SCOPE_AGENT) < t)
          __builtin_amdgcn_s_sleep(1);
      }
      __syncthreads();
      __builtin_amdgcn_fence(__ATOMIC_ACQUIRE, "agent");
      {
        const float* hp = Hbuf + (size_t)(t - 1) * H_DIM;
        float2 hv = *(const float2*)(hp + tid * 2);
        int sl = (t - 1) & 7;
        hring[sl][tid * 2]     = (_Float16)hv.x;
        hring[sl][tid * 2 + 1] = (_Float16)hv.y;
        if (tid < 8) cring[sl][tid] = Cbuf[(size_t)(t - 1) * H_DIM + blk * 8 + tid];
      }
      __syncthreads();
    }

    // ---- late Uw passes (start == t-1, or garbage start: finite fallback) ----
#pragma unroll
    for (int w = 0; w < WNUM; ++w)
      if (val[w] && st[w] > t - 2) PASS(&hring[(t - 1) & 7][0], wUw, accw[w]);

    // ---- c_w compute + publish ----
#pragma unroll
    for (int w = 0; w < WNUM; ++w)
      if (val[w]) {
        float red = accw[w];
        red += __shfl_xor(red, 1); red += __shfl_xor(red, 2); red += __shfl_xor(red, 4);
        if (rg == 0 && cg < 6) scr[wv][cg] = red;
#pragma unroll
        for (int kl = 0; kl < 2; ++kl) {
          float f_ = scr[wv][0 + kl] + gwx[w][0 + kl];
          float i_ = scr[wv][2 + kl] + gwx[w][2 + kl];
          float g_ = scr[wv][4 + kl] + gwx[w][4 + kl];
          float cs = cring[st[w] & 7][wv * 2 + kl];
          float cw = sigm(f_) * cs + sigm(i_) * tanhfast(g_);
          if (lane == 0) {
            cwown[wv][w][kl] = cw;
            cwBuf[(size_t)(t & 1) * WNUM * H_DIM + w * H_DIM + kbase + kl] = cw;
          }
        }
      }
    __builtin_amdgcn_fence(__ATOMIC_RELEASE, "agent");
    __syncthreads();
    if (tid == 0)
      __hip_atomic_store(cwFlag + blk * 16, t + 1, __ATOMIC_RELEASE, __HIP_MEMORY_SCOPE_AGENT);

    // ---- gates (overlaps other WGs' c_w flight) ----
    float ig[2], og[2], gg[2];
    {
      float accu;
      PASS(&hring[(t - 1) & 7][0], wU, accu);
      float red = accu;
      red += __shfl_xor(red, 1); red += __shfl_xor(red, 2); red += __shfl_xor(red, 4);
      if (rg == 0 && cg < 6) scr[wv][cg] = red;
#pragma unroll
      for (int kl = 0; kl < 2; ++kl) {
        ig[kl] = sigm(scr[wv][0 + kl] + aT[0 + kl]);
        og[kl] = sigm(scr[wv][2 + kl] + aT[2 + kl]);
        gg[kl] = tanhfast(scr[wv][4 + kl] + aT[4 + kl]);
      }
    }

    // ---- wait for all c_w, fill LDS copy ----
    if (tid < 64) {
      int* fp = cwFlag + tid * 16;
      int tgt = t + 1;
      while (__hip_atomic_load(fp, __ATOMIC_RELAXED, __HIP_MEMORY_SCOPE_AGENT) < tgt)
        __builtin_amdgcn_s_sleep(1);
    }
    __syncthreads();
    __builtin_amdgcn_fence(__ATOMIC_ACQUIRE, "agent");
    {
      const float* cb = cwBuf + (size_t)(t & 1) * WNUM * H_DIM;
#pragma unroll
      for (int w = 0; w < WNUM; ++w) {
        float x0 = 0.f, x1 = 0.f;
        if (val[w]) {
          float2 cv = *(const float2*)(cb + w * H_DIM + tid * 2);
          x0 = cv.x; x1 = cv.y;
        }
        cwlds[w][tid * 2]     = (_Float16)x0;
        cwlds[w][tid * 2 + 1] = (_Float16)x1;
      }
    }
    __syncthreads();

    // ---- alpha = sigmoid(Axa + c_w @ Ua), own columns ----
    float aw[WNUM][2] = {{0.f,0.f},{0.f,0.f},{0.f,0.f},{0.f,0.f}};
#pragma unroll
    for (int w = 0; w < WNUM; ++w)
      if (val[w]) {
        float acca;
        PASS(&cwlds[w][0], wUa, acca);
        float red = acca;
        red += __shfl_xor(red, 1); red += __shfl_xor(red, 2); red += __shfl_xor(red, 4);
        if (rg == 0 && cg < 2) scr[wv][cg] = red;
        aw[w][0] = scr[wv][0]; aw[w][1] = scr[wv][1];
      }

    // ---- combine (exp-weighted soft cell or plain LSTM cell) ----
#pragma unroll
    for (int kl = 0; kl < 2; ++kl) {
      int kg = kbase + kl;
      float e0 = __expf(ig[kl]);
      float num = e0 * gg[kl], den = e0;
#pragma unroll
      for (int w = 0; w < WNUM; ++w)
        if (val[w]) {
          float al = sigm(aw[w][kl] + axaT[kl]);
          float ew = __expf(al);
          num += ew * cwown[wv][w][kl];
          den += ew;
        }
      float cprev = cring[(t - 1) & 7][wv * 2 + kl];
      float csoft = num / den;
      float cplain = (1.f - ig[kl]) * cprev + ig[kl] * gg[kl];
      float c1 = anyw ? csoft : cplain;
      float h1 = og[kl] * tanhfast(c1);
      if (lane == kl) {
        Hbuf[(size_t)t * H_DIM + kg] = h1;
        Cbuf[(size_t)t * H_DIM + kg] = c1;
        if (fm) {
          ((float*)outp)[(size_t)t * 1024 + kg] = h1;
          ((float*)outp)[(size_t)t * 1024 + 512 + kg] = c1;
        } else {
          ((bf16*)outp)[(size_t)t * 1024 + kg] = __float2bfloat16(h1);
          ((bf16*)outp)[(size_t)t * 1024 + 512 + kg] = __float2bfloat16(c1);
        }
      }
    }
    __builtin_amdgcn_fence(__ATOMIC_RELEASE, "agent");
    __syncthreads();
    if (tid == 0)
      __hip_atomic_store(Hflag + blk * 16, t + 1, __ATOMIC_RELEASE, __HIP_MEMORY_SCOPE_AGENT);
  }
}

extern "C" void kernel_launch(void* const* d_in, const int* in_sizes, int n_in,
                              void* d_out, int out_size, void* d_ws, size_t ws_size,
                              hipStream_t stream) {
  const void* x    = d_in[0];
  const int* wids  = (const int*)d_in[1];
  const int* wst   = (const int*)d_in[2];
  const void* wmsk = d_in[3];
  const void* h0   = d_in[4];
  const void* c0   = d_in[5];
  const void* emb  = d_in[6];
  const void* W    = d_in[7];
  const void* U    = d_in[8];
  const void* b    = d_in[9];
  const void* Wa   = d_in[10];
  const void* Ua   = d_in[11];
  const void* ba   = d_in[12];
  const void* Ww   = d_in[13];
  const void* Uw   = d_in[14];
  const void* bw   = d_in[15];
  unsigned char* ws = (unsigned char*)d_ws;
  (void)in_sizes; (void)n_in; (void)out_size; (void)ws_size;

  k_init<<<1, 256, 0, stream>>>(wmsk, h0, ws);
  k_xgemm<<<512, 256, 0, stream>>>(x, W, b, Wa, ba, ws);
  k_wgemm<<<2048, 256, 0, stream>>>(wids, wmsk, emb, Ww, bw, ws);
  k_seq<<<NBLK, 256, 0, stream>>>(wst, wmsk, h0, c0, U, Uw, Ua, ws, d_out);
}

// Round 3
// 19237.004 us; speedup vs baseline: 3.0874x; 3.0874x over previous
//
#include <hip/hip_runtime.h>
#include <hip/hip_bf16.h>

typedef __hip_bfloat16 bf16;
typedef _Float16 half2v __attribute__((ext_vector_type(2)));

#define T_LEN 4096
#define D_IN  128
#define H_DIM 512
#define E_DIM 256
#define WNUM  4
#define G3    1536
#define NBLK  64   // sequential workgroups (1 per CU => all co-resident)

// ---- workspace layout (bytes) ----
#define OFF_MODE   0ull
#define OFF_FMODE  4ull
#define OFF_HPK    16384ull                                   // u32 [8][512] packed (tag,f16 h)
#define OFF_CWPK   (OFF_HPK + 8ull*512ull*4ull)               // u32 [2][4][512] packed (tag,f16 cw)
#define OFF_A      65536ull                                   // bf16 [4096][1536]
#define OFF_AXA    (OFF_A   + 4096ull*1536ull*2ull)           // bf16 [4096][512]
#define OFF_GW0    (OFF_AXA + 4096ull*512ull*2ull)            // bf16 [16384][1536]
// total ~67 MB

__device__ __forceinline__ float bf2f(bf16 h) {
  unsigned short u = __builtin_bit_cast(unsigned short, h);
  unsigned int i = ((unsigned int)u) << 16;
  return __builtin_bit_cast(float, i);
}
__device__ __forceinline__ unsigned short f2bfbits(float f) {
  return __builtin_bit_cast(unsigned short, __float2bfloat16(f));
}
__device__ __forceinline__ unsigned int packbf(float a, float b) {
  return (unsigned int)f2bfbits(a) | ((unsigned int)f2bfbits(b) << 16);
}
__device__ __forceinline__ float sigm(float x) { return 1.f / (1.f + __expf(-x)); }
__device__ __forceinline__ float tanhfast(float x) { return 1.f - 2.f / (__expf(2.f * x) + 1.f); }

#if __has_builtin(__builtin_amdgcn_fdot2)
__device__ __forceinline__ float fdot2(half2v a, half2v b, float c) {
  return __builtin_amdgcn_fdot2(a, b, c, false);
}
#else
__device__ __forceinline__ float fdot2(half2v a, half2v b, float c) {
  return c + (float)a.x * (float)b.x + (float)a.y * (float)b.y;
}
#endif

__device__ __forceinline__ half2v make2(float a, float b) {
  half2v r; r.x = (_Float16)a; r.y = (_Float16)b; return r;
}

// ---- packed transfer word: high16 = tag (t+1), low16 = f16 value ----
__device__ __forceinline__ unsigned int pack16(float v, int tag) {
  _Float16 h = (_Float16)v;
  unsigned short b = __builtin_bit_cast(unsigned short, h);
  return ((unsigned int)tag << 16) | (unsigned int)b;
}
__device__ __forceinline__ _Float16 unpack16(unsigned int v) {
  return __builtin_bit_cast(_Float16, (unsigned short)(v & 0xffffu));
}
__device__ __forceinline__ unsigned int aload(const unsigned int* p) {
  return __hip_atomic_load(p, __ATOMIC_RELAXED, __HIP_MEMORY_SCOPE_AGENT);
}
__device__ __forceinline__ void astore(unsigned int* p, unsigned int v) {
  __hip_atomic_store(p, v, __ATOMIC_RELAXED, __HIP_MEMORY_SCOPE_AGENT);
}

// ---- dtype-adaptive loads: fm==1 -> float32, fm==0 -> bf16 ----
__device__ __forceinline__ float ldf(const void* p, size_t i, int fm) {
  return fm ? ((const float*)p)[i] : bf2f(((const bf16*)p)[i]);
}
__device__ __forceinline__ void ld8(const void* p, size_t i, int fm, float* o) {
  if (fm) {
    const float* q = (const float*)p + i;
    float4 a = *(const float4*)q, b2 = *(const float4*)(q + 4);
    o[0]=a.x; o[1]=a.y; o[2]=a.z; o[3]=a.w; o[4]=b2.x; o[5]=b2.y; o[6]=b2.z; o[7]=b2.w;
  } else {
    uint4 raw = *(const uint4*)((const bf16*)p + i);
    unsigned int u[4] = {raw.x, raw.y, raw.z, raw.w};
#pragma unroll
    for (int j = 0; j < 4; ++j) {
      o[2*j]   = __builtin_bit_cast(float, u[j] << 16);
      o[2*j+1] = __builtin_bit_cast(float, u[j] & 0xffff0000u);
    }
  }
}
__device__ __forceinline__ void ld4(const void* p, size_t i, int fm, float* o) {
  if (fm) {
    float4 a = *(const float4*)((const float*)p + i);
    o[0]=a.x; o[1]=a.y; o[2]=a.z; o[3]=a.w;
  } else {
    uint2 raw = *(const uint2*)((const bf16*)p + i);
    o[0] = __builtin_bit_cast(float, raw.x << 16);
    o[1] = __builtin_bit_cast(float, raw.x & 0xffff0000u);
    o[2] = __builtin_bit_cast(float, raw.y << 16);
    o[3] = __builtin_bit_cast(float, raw.y & 0xffff0000u);
  }
}
// mask read: mode 0=int32, 1=byte, 2=bf16 halfword, 3=f32 dword
__device__ __forceinline__ bool readmask(const void* p, int idx, int mode) {
  switch (mode) {
    case 0:  return ((const int*)p)[idx] != 0;
    case 1:  return ((const unsigned char*)p)[idx] != 0;
    case 2:  return ((const unsigned short*)p)[idx] != 0;
    default: return ((const unsigned int*)p)[idx] != 0;
  }
}

// ============ init: detect mask dtype + float width ============
__global__ void k_init(const void* __restrict__ mask_p, const void* __restrict__ h0_p,
                       unsigned char* __restrict__ ws) {
  int tid = threadIdx.x;
  __shared__ int s_b1, s_bf, s_f32, s_votes;
  if (tid == 0) { s_b1 = 0; s_bf = 0; s_f32 = 0; s_votes = 0; }
  __syncthreads();
  int b1 = 0, bfh = 0, f32h = 0;
  const unsigned int* dv = (const unsigned int*)mask_p;
  for (int i = tid; i < 4096; i += 256) {
    unsigned int d = dv[i];
    if (((d >> 8) & 0xFFu) == 1u || ((d >> 16) & 0xFFu) == 1u || ((d >> 24) & 0xFFu) == 1u) b1 = 1;
    if ((d & 0xFFFFu) == 0x3F80u) bfh = 1;
    if (d == 0x3F800000u) f32h = 1;
  }
  if (b1)  atomicOr(&s_b1, 1);
  if (bfh) atomicOr(&s_bf, 1);
  if (f32h) atomicOr(&s_f32, 1);
  if (tid < 128) {
    unsigned int d = ((const unsigned int*)h0_p)[tid];
    int e = (int)((d >> 23) & 0xFF);
    if (e >= 100 && e <= 140) atomicAdd(&s_votes, 1);
  }
  __syncthreads();
  if (tid == 0) {
    int mode = s_b1 ? 1 : (s_bf ? 2 : (s_f32 ? 3 : 0));
    *(int*)(ws + OFF_MODE)  = mode;
    *(int*)(ws + OFF_FMODE) = (s_votes >= 64) ? 1 : 0;
  }
}

// ============ A = x@W + b ; Axa = x@Wa + ba  (bf16 out) ============
__global__ __launch_bounds__(256) void k_xgemm(
    const void* __restrict__ x, const void* __restrict__ W, const void* __restrict__ b,
    const void* __restrict__ Wa, const void* __restrict__ ba, unsigned char* __restrict__ ws) {
  const int fm = *(const int*)(ws + OFF_FMODE);
  bf16* A   = (bf16*)(ws + OFF_A);
  bf16* Axa = (bf16*)(ws + OFF_AXA);
  const int tid = threadIdx.x;
  const int t0 = blockIdx.x * 8;
  __shared__ float sx[8][128];
  {
    int flat = tid * 4, r = flat >> 7, k = flat & 127;
    ld4(x, (size_t)(t0 + r) * D_IN + k, fm, &sx[r][k]);
  }
  __syncthreads();
  const bool isA = (tid < 192);
  const int c0 = isA ? tid * 8 : (tid - 192) * 8;
  const void* M = isA ? W : Wa;
  const int ldm = isA ? G3 : H_DIM;
  float acc[8][8];
#pragma unroll
  for (int r = 0; r < 8; ++r)
#pragma unroll
    for (int c = 0; c < 8; ++c) acc[r][c] = 0.f;
  for (int k = 0; k < D_IN; ++k) {
    float wv[8];
    ld8(M, (size_t)k * ldm + c0, fm, wv);
#pragma unroll
    for (int r = 0; r < 8; ++r) {
      float xv = sx[r][k];
#pragma unroll
      for (int c = 0; c < 8; ++c) acc[r][c] += xv * wv[c];
    }
  }
  float bias[8];
  ld8(isA ? b : ba, c0, fm, bias);
#pragma unroll
  for (int r = 0; r < 8; ++r) {
    uint4 o;
    o.x = packbf(acc[r][0] + bias[0], acc[r][1] + bias[1]);
    o.y = packbf(acc[r][2] + bias[2], acc[r][3] + bias[3]);
    o.z = packbf(acc[r][4] + bias[4], acc[r][5] + bias[5]);
    o.w = packbf(acc[r][6] + bias[6], acc[r][7] + bias[7]);
    if (isA) *(uint4*)(A + (size_t)(t0 + r) * G3 + c0) = o;
    else     *(uint4*)(Axa + (size_t)(t0 + r) * H_DIM + c0) = o;
  }
}

// ============ GW0[row] = emb[wid]@Ww + bw  (masked rows only, bf16 out) ============
__global__ __launch_bounds__(256) void k_wgemm(
    const int* __restrict__ wids, const void* __restrict__ wmask,
    const void* __restrict__ emb, const void* __restrict__ Ww, const void* __restrict__ bw,
    unsigned char* __restrict__ ws) {
  const int mode = *(const int*)(ws + OFF_MODE);
  const int fm   = *(const int*)(ws + OFF_FMODE);
  bf16* GW0 = (bf16*)(ws + OFF_GW0);
  const int tid = threadIdx.x;
  const int r0 = blockIdx.x * 8;
  bool m[8]; bool any = false;
#pragma unroll
  for (int r = 0; r < 8; ++r) {
    bool mm = readmask(wmask, r0 + r, mode);
    m[r] = mm; any |= mm;
  }
  if (!any) return;
  __shared__ float se[8][E_DIM];
#pragma unroll
  for (int r = 0; r < 8; ++r)
    if (m[r]) {
      int wid = wids[r0 + r];
      se[r][tid] = ldf(emb, (size_t)wid * E_DIM + tid, fm);
    }
  __syncthreads();
  if (tid < 192) {
    const int c0 = tid * 8;
    float acc[8][8];
#pragma unroll
    for (int r = 0; r < 8; ++r)
#pragma unroll
      for (int c = 0; c < 8; ++c) acc[r][c] = 0.f;
    for (int k = 0; k < E_DIM; ++k) {
      float wv[8];
      ld8(Ww, (size_t)k * G3 + c0, fm, wv);
#pragma unroll
      for (int r = 0; r < 8; ++r)
        if (m[r]) {
          float xv = se[r][k];
#pragma unroll
          for (int c = 0; c < 8; ++c) acc[r][c] += xv * wv[c];
        }
    }
    float bias[8];
    ld8(bw, c0, fm, bias);
#pragma unroll
    for (int r = 0; r < 8; ++r)
      if (m[r]) {
        uint4 o;
        o.x = packbf(acc[r][0] + bias[0], acc[r][1] + bias[1]);
        o.y = packbf(acc[r][2] + bias[2], acc[r][3] + bias[3]);
        o.z = packbf(acc[r][4] + bias[4], acc[r][5] + bias[5]);
        o.w = packbf(acc[r][6] + bias[6], acc[r][7] + bias[7]);
        *(uint4*)(GW0 + (size_t)(r0 + r) * G3 + c0) = o;
      }
  }
}

// ---- per-wave dot pass: lane(cg=lane>>3, rg=lane&7); lane rows {64m+8rg..+7} ----
#define PASS(slotptr, wt, accvar) do {                                  \
    float _acc = 0.f;                                                   \
    const _Float16* _vp = (slotptr) + 8 * rg;                           \
    _Pragma("unroll")                                                   \
    for (int _m = 0; _m < 8; ++_m) {                                    \
      float4 _raw = *(const float4*)(_vp + 64 * _m);                    \
      half2v _h0 = __builtin_bit_cast(half2v, _raw.x);                  \
      half2v _h1 = __builtin_bit_cast(half2v, _raw.y);                  \
      half2v _h2 = __builtin_bit_cast(half2v, _raw.z);                  \
      half2v _h3 = __builtin_bit_cast(half2v, _raw.w);                  \
      _acc = fdot2(_h0, wt[_m * 4 + 0], _acc);                          \
      _acc = fdot2(_h1, wt[_m * 4 + 1], _acc);                          \
      _acc = fdot2(_h2, wt[_m * 4 + 2], _acc);                          \
      _acc = fdot2(_h3, wt[_m * 4 + 3], _acc);                          \
    }                                                                   \
    accvar = _acc;                                                      \
  } while (0)

// ============ sequential lattice recurrence: 64 persistent WGs, fence-free ============
__global__ __launch_bounds__(256, 1) void k_seq(
    const int* __restrict__ wstarts, const void* __restrict__ wmask,
    const void* __restrict__ h0_p, const void* __restrict__ c0_p,
    const void* __restrict__ U, const void* __restrict__ Uw, const void* __restrict__ Ua,
    unsigned char* __restrict__ ws, void* __restrict__ outp) {
  const int tid = threadIdx.x;
  const int blk = blockIdx.x;
  const int wv = tid >> 6;
  const int lane = tid & 63;
  const int cg = lane >> 3;
  const int rg = lane & 7;
  const int kbase = blk * 8 + wv * 2;  // global k for kl=0 of this wave

  const int mode = *(const int*)(ws + OFF_MODE);
  const int fm   = *(const int*)(ws + OFF_FMODE);
  const bf16* A   = (const bf16*)(ws + OFF_A);
  const bf16* Axa = (const bf16*)(ws + OFF_AXA);
  const bf16* GW0 = (const bf16*)(ws + OFF_GW0);
  unsigned int* HPK  = (unsigned int*)(ws + OFF_HPK);   // [8][512]
  unsigned int* CWPK = (unsigned int*)(ws + OFF_CWPK);  // [2][4][512]

  __shared__ __align__(16) _Float16 hring[8][520];    // full h ring (f16, +8 pad)
  __shared__ __align__(16) _Float16 cwlds[WNUM][520]; // full c_w per word (f16)
  __shared__ float cring[8][8];                       // own 8 c-columns ring (f32, local only)
  __shared__ float scr[4][8];                         // per-wave reduce scratch
  __shared__ float cwown[4][WNUM][2];                 // own c_w values per wave (f32)

  // ---- zero-init LDS (defense) ----
  {
    _Float16* hz = &hring[0][0];
    for (int i = tid; i < 8 * 520; i += 256) hz[i] = (_Float16)0.f;
    _Float16* cz = &cwlds[0][0];
    for (int i = tid; i < WNUM * 520; i += 256) cz[i] = (_Float16)0.f;
    if (tid < 64) (&cring[0][0])[tid] = 0.f;
    if (tid < 32) (&scr[0][0])[tid] = 0.f;
    if (tid < 32) (&cwown[0][0][0])[tid] = 0.f;
  }

  // ---- persistent weights in VGPRs (f16 pairs) ----
  half2v wU[32], wUw[32], wUa[32];
  {
    const int gate = cg >> 1;
    const int klw = cg & 1;
    const int colU = gate * H_DIM + (kbase + klw);  // valid when cg<6
    const int colA = kbase + cg;                    // valid when cg<2
#pragma unroll
    for (int mq = 0; mq < 32; ++mq) {
      int mm = mq >> 2, q = mq & 3;
      int r = 64 * mm + 8 * rg + 2 * q;
      float u0 = 0, u1 = 0, v0 = 0, v1 = 0, a0 = 0, a1 = 0;
      if (cg < 6) {
        u0 = ldf(U, (size_t)r * G3 + colU, fm);  u1 = ldf(U, (size_t)(r + 1) * G3 + colU, fm);
        v0 = ldf(Uw, (size_t)r * G3 + colU, fm); v1 = ldf(Uw, (size_t)(r + 1) * G3 + colU, fm);
      }
      if (cg < 2) {
        a0 = ldf(Ua, (size_t)r * H_DIM + colA, fm); a1 = ldf(Ua, (size_t)(r + 1) * H_DIM + colA, fm);
      }
      wU[mq] = make2(u0, u1); wUw[mq] = make2(v0, v1); wUa[mq] = make2(a0, a1);
    }
  }
  __syncthreads();

  // ---- preload ring slot 7 with h0/c0 (the "t-1" state of step 0) ----
  {
    int i = tid * 2;
    hring[7][i]     = (_Float16)ldf(h0_p, i, fm);
    hring[7][i + 1] = (_Float16)ldf(h0_p, i + 1, fm);
    if (tid < 8) cring[7][tid] = ldf(c0_p, blk * 8 + tid, fm);
  }
  __syncthreads();

  for (int t = 0; t < T_LEN; ++t) {
    // ---- word metadata (uniform broadcast loads) ----
    int st[WNUM]; bool val[WNUM]; bool anyw = false;
#pragma unroll
    for (int w = 0; w < WNUM; ++w) {
      st[w] = wstarts[t * WNUM + w];
      bool mmk = readmask(wmask, t * WNUM + w, mode);
      val[w] = mmk; anyw |= mmk;
    }
    // ---- prefetch per-wave scalar terms (plain cached loads) ----
    float gwx[WNUM][6], aT[6], axaT[2];
#pragma unroll
    for (int w = 0; w < WNUM; ++w)
      if (val[w]) {
#pragma unroll
        for (int g3 = 0; g3 < 3; ++g3)
#pragma unroll
          for (int kl = 0; kl < 2; ++kl)
            gwx[w][g3 * 2 + kl] =
                bf2f(GW0[(size_t)(t * WNUM + w) * G3 + g3 * H_DIM + kbase + kl]);
      }
#pragma unroll
    for (int g3 = 0; g3 < 3; ++g3)
#pragma unroll
      for (int kl = 0; kl < 2; ++kl)
        aT[g3 * 2 + kl] = bf2f(A[(size_t)t * G3 + g3 * H_DIM + kbase + kl]);
#pragma unroll
    for (int kl = 0; kl < 2; ++kl)
      axaT[kl] = bf2f(Axa[(size_t)t * H_DIM + kbase + kl]);

    // ---- P1: EARLY words (st <= t-2): compute c_w and publish before h-wait ----
    unsigned int* cwSlot = CWPK + (size_t)(t & 1) * WNUM * H_DIM;
#pragma unroll
    for (int w = 0; w < WNUM; ++w)
      if (val[w] && st[w] <= t - 2) {
        float accw;
        PASS(&hring[st[w] & 7][0], wUw, accw);
        float red = accw;
        red += __shfl_xor(red, 1); red += __shfl_xor(red, 2); red += __shfl_xor(red, 4);
        if (rg == 0 && cg < 6) scr[wv][cg] = red;
#pragma unroll
        for (int kl = 0; kl < 2; ++kl) {
          float f_ = scr[wv][0 + kl] + gwx[w][0 + kl];
          float i_ = scr[wv][2 + kl] + gwx[w][2 + kl];
          float g_ = scr[wv][4 + kl] + gwx[w][4 + kl];
          float cs = cring[st[w] & 7][wv * 2 + kl];
          float cw = sigm(f_) * cs + sigm(i_) * tanhfast(g_);
          if (lane == 0) {
            cwown[wv][w][kl] = cw;
            astore(cwSlot + w * H_DIM + kbase + kl, pack16(cw, t + 1));
          }
        }
      }

    // ---- W1: poll h[t-1] (self-validating packed words), fill ring ----
    if (t > 0) {
      const unsigned int expect = (unsigned int)t;   // tag of h[t-1]
      const unsigned int* hp = HPK + (size_t)((t - 1) & 7) * H_DIM + tid * 2;
      unsigned int v0, v1;
      for (;;) {
        v0 = aload(hp);
        v1 = aload(hp + 1);
        if ((v0 >> 16) == expect && (v1 >> 16) == expect) break;
      }
      int sl = (t - 1) & 7;
      hring[sl][tid * 2]     = unpack16(v0);
      hring[sl][tid * 2 + 1] = unpack16(v1);
    }
    __syncthreads();   // B1

    // ---- P2: LATE words (st == t-1): compute c_w and publish ----
#pragma unroll
    for (int w = 0; w < WNUM; ++w)
      if (val[w] && st[w] > t - 2) {
        float accw;
        PASS(&hring[(t - 1) & 7][0], wUw, accw);
        float red = accw;
        red += __shfl_xor(red, 1); red += __shfl_xor(red, 2); red += __shfl_xor(red, 4);
        if (rg == 0 && cg < 6) scr[wv][cg] = red;
#pragma unroll
        for (int kl = 0; kl < 2; ++kl) {
          float f_ = scr[wv][0 + kl] + gwx[w][0 + kl];
          float i_ = scr[wv][2 + kl] + gwx[w][2 + kl];
          float g_ = scr[wv][4 + kl] + gwx[w][4 + kl];
          float cs = cring[st[w] & 7][wv * 2 + kl];
          float cw = sigm(f_) * cs + sigm(i_) * tanhfast(g_);
          if (lane == 0) {
            cwown[wv][w][kl] = cw;
            astore(cwSlot + w * H_DIM + kbase + kl, pack16(cw, t + 1));
          }
        }
      }

    // ---- gates (overlaps c_w flight of other WGs) ----
    float ig[2], og[2], gg[2];
    {
      float accu;
      PASS(&hring[(t - 1) & 7][0], wU, accu);
      float red = accu;
      red += __shfl_xor(red, 1); red += __shfl_xor(red, 2); red += __shfl_xor(red, 4);
      if (rg == 0 && cg < 6) scr[wv][cg] = red;
#pragma unroll
      for (int kl = 0; kl < 2; ++kl) {
        ig[kl] = sigm(scr[wv][0 + kl] + aT[0 + kl]);
        og[kl] = sigm(scr[wv][2 + kl] + aT[2 + kl]);
        gg[kl] = tanhfast(scr[wv][4 + kl] + aT[4 + kl]);
      }
    }

    // ---- W2: poll c_w for valid words, fill LDS ----
#pragma unroll
    for (int w = 0; w < WNUM; ++w)
      if (val[w]) {
        const unsigned int expect = (unsigned int)(t + 1);
        const unsigned int* cp = cwSlot + w * H_DIM + tid * 2;
        unsigned int v0, v1;
        for (;;) {
          v0 = aload(cp);
          v1 = aload(cp + 1);
          if ((v0 >> 16) == expect && (v1 >> 16) == expect) break;
        }
        cwlds[w][tid * 2]     = unpack16(v0);
        cwlds[w][tid * 2 + 1] = unpack16(v1);
      }
    __syncthreads();   // B2

    // ---- alpha = sigmoid(Axa + c_w @ Ua), own columns ----
    float aw[WNUM][2] = {{0.f,0.f},{0.f,0.f},{0.f,0.f},{0.f,0.f}};
#pragma unroll
    for (int w = 0; w < WNUM; ++w)
      if (val[w]) {
        float acca;
        PASS(&cwlds[w][0], wUa, acca);
        float red = acca;
        red += __shfl_xor(red, 1); red += __shfl_xor(red, 2); red += __shfl_xor(red, 4);
        if (rg == 0 && cg < 2) scr[wv][cg] = red;
        aw[w][0] = scr[wv][0]; aw[w][1] = scr[wv][1];
      }

    // ---- combine + publish h[t] ----
#pragma unroll
    for (int kl = 0; kl < 2; ++kl) {
      int kg = kbase + kl;
      float e0 = __expf(ig[kl]);
      float num = e0 * gg[kl], den = e0;
#pragma unroll
      for (int w = 0; w < WNUM; ++w)
        if (val[w]) {
          float al = sigm(aw[w][kl] + axaT[kl]);
          float ew = __expf(al);
          num += ew * cwown[wv][w][kl];
          den += ew;
        }
      float cprev = cring[(t - 1) & 7][wv * 2 + kl];
      float csoft = num / den;
      float cplain = (1.f - ig[kl]) * cprev + ig[kl] * gg[kl];
      float c1 = anyw ? csoft : cplain;
      float h1 = og[kl] * tanhfast(c1);
      if (lane == kl) {
        cring[t & 7][wv * 2 + kl] = c1;
        astore(HPK + (size_t)(t & 7) * H_DIM + kg, pack16(h1, t + 1));
        if (fm) {
          ((float*)outp)[(size_t)t * 1024 + kg] = h1;
          ((float*)outp)[(size_t)t * 1024 + 512 + kg] = c1;
        } else {
          ((bf16*)outp)[(size_t)t * 1024 + kg] = __float2bfloat16(h1);
          ((bf16*)outp)[(size_t)t * 1024 + 512 + kg] = __float2bfloat16(c1);
        }
      }
    }
  }
}

extern "C" void kernel_launch(void* const* d_in, const int* in_sizes, int n_in,
                              void* d_out, int out_size, void* d_ws, size_t ws_size,
                              hipStream_t stream) {
  const void* x    = d_in[0];
  const int* wids  = (const int*)d_in[1];
  const int* wst   = (const int*)d_in[2];
  const void* wmsk = d_in[3];
  const void* h0   = d_in[4];
  const void* c0   = d_in[5];
  const void* emb  = d_in[6];
  const void* W    = d_in[7];
  const void* U    = d_in[8];
  const void* b    = d_in[9];
  const void* Wa   = d_in[10];
  const void* Ua   = d_in[11];
  const void* ba   = d_in[12];
  const void* Ww   = d_in[13];
  const void* Uw   = d_in[14];
  const void* bw   = d_in[15];
  unsigned char* ws = (unsigned char*)d_ws;
  (void)in_sizes; (void)n_in; (void)out_size; (void)ws_size;

  k_init<<<1, 256, 0, stream>>>(wmsk, h0, ws);
  k_xgemm<<<512, 256, 0, stream>>>(x, W, b, Wa, ba, ws);
  k_wgemm<<<2048, 256, 0, stream>>>(wids, wmsk, emb, Ww, bw, ws);
  k_seq<<<NBLK, 256, 0, stream>>>(wst, wmsk, h0, c0, U, Uw, Ua, ws, d_out);
}

// Round 4
// 17806.052 us; speedup vs baseline: 3.3355x; 1.0804x over previous
//
#include <hip/hip_runtime.h>
#include <hip/hip_bf16.h>

typedef __hip_bfloat16 bf16;
typedef _Float16 half2v __attribute__((ext_vector_type(2)));

#define T_LEN 4096
#define D_IN  128
#define H_DIM 512
#define E_DIM 256
#define WNUM  4
#define G3    1536
#define NBLK  64   // sequential workgroups (1 per CU => all co-resident)

// ---- workspace layout (bytes) ----
#define OFF_MODE   0ull
#define OFF_FMODE  4ull
#define OFF_HPK    16384ull                                   // u32 [8][512] packed (tag,f16 h)
#define OFF_CWPK   (OFF_HPK + 8ull*512ull*4ull)               // u32 [2][4][512] packed (tag,f16 cw)
#define OFF_A      65536ull                                   // bf16 [4096][1536]
#define OFF_AXA    (OFF_A   + 4096ull*1536ull*2ull)           // bf16 [4096][512]
#define OFF_GW0    (OFF_AXA + 4096ull*512ull*2ull)            // bf16 [16384][1536]
// total ~67 MB

__device__ __forceinline__ float bf2f(bf16 h) {
  unsigned short u = __builtin_bit_cast(unsigned short, h);
  unsigned int i = ((unsigned int)u) << 16;
  return __builtin_bit_cast(float, i);
}
__device__ __forceinline__ unsigned short f2bfbits(float f) {
  return __builtin_bit_cast(unsigned short, __float2bfloat16(f));
}
__device__ __forceinline__ unsigned int packbf(float a, float b) {
  return (unsigned int)f2bfbits(a) | ((unsigned int)f2bfbits(b) << 16);
}
__device__ __forceinline__ float sigm(float x) { return 1.f / (1.f + __expf(-x)); }
__device__ __forceinline__ float tanhfast(float x) { return 1.f - 2.f / (__expf(2.f * x) + 1.f); }

#if __has_builtin(__builtin_amdgcn_fdot2)
__device__ __forceinline__ float fdot2(half2v a, half2v b, float c) {
  return __builtin_amdgcn_fdot2(a, b, c, false);
}
#else
__device__ __forceinline__ float fdot2(half2v a, half2v b, float c) {
  return c + (float)a.x * (float)b.x + (float)a.y * (float)b.y;
}
#endif

__device__ __forceinline__ half2v make2(float a, float b) {
  half2v r; r.x = (_Float16)a; r.y = (_Float16)b; return r;
}

// ---- packed transfer word: high16 = tag (t+1), low16 = f16 value ----
__device__ __forceinline__ unsigned int pack16(float v, int tag) {
  _Float16 h = (_Float16)v;
  unsigned short b = __builtin_bit_cast(unsigned short, h);
  return ((unsigned int)tag << 16) | (unsigned int)b;
}
__device__ __forceinline__ _Float16 unpack16(unsigned int v) {
  return __builtin_bit_cast(_Float16, (unsigned short)(v & 0xffffu));
}
__device__ __forceinline__ unsigned int aload(const unsigned int* p) {
  return __hip_atomic_load(p, __ATOMIC_RELAXED, __HIP_MEMORY_SCOPE_AGENT);
}
__device__ __forceinline__ void astore(unsigned int* p, unsigned int v) {
  __hip_atomic_store(p, v, __ATOMIC_RELAXED, __HIP_MEMORY_SCOPE_AGENT);
}

// ---- dtype-adaptive loads: fm==1 -> float32, fm==0 -> bf16 ----
__device__ __forceinline__ float ldf(const void* p, size_t i, int fm) {
  return fm ? ((const float*)p)[i] : bf2f(((const bf16*)p)[i]);
}
__device__ __forceinline__ void ld8(const void* p, size_t i, int fm, float* o) {
  if (fm) {
    const float* q = (const float*)p + i;
    float4 a = *(const float4*)q, b2 = *(const float4*)(q + 4);
    o[0]=a.x; o[1]=a.y; o[2]=a.z; o[3]=a.w; o[4]=b2.x; o[5]=b2.y; o[6]=b2.z; o[7]=b2.w;
  } else {
    uint4 raw = *(const uint4*)((const bf16*)p + i);
    unsigned int u[4] = {raw.x, raw.y, raw.z, raw.w};
#pragma unroll
    for (int j = 0; j < 4; ++j) {
      o[2*j]   = __builtin_bit_cast(float, u[j] << 16);
      o[2*j+1] = __builtin_bit_cast(float, u[j] & 0xffff0000u);
    }
  }
}
__device__ __forceinline__ void ld4(const void* p, size_t i, int fm, float* o) {
  if (fm) {
    float4 a = *(const float4*)((const float*)p + i);
    o[0]=a.x; o[1]=a.y; o[2]=a.z; o[3]=a.w;
  } else {
    uint2 raw = *(const uint2*)((const bf16*)p + i);
    o[0] = __builtin_bit_cast(float, raw.x << 16);
    o[1] = __builtin_bit_cast(float, raw.x & 0xffff0000u);
    o[2] = __builtin_bit_cast(float, raw.y << 16);
    o[3] = __builtin_bit_cast(float, raw.y & 0xffff0000u);
  }
}
// mask read: mode 0=int32, 1=byte, 2=bf16 halfword, 3=f32 dword
__device__ __forceinline__ bool readmask(const void* p, int idx, int mode) {
  switch (mode) {
    case 0:  return ((const int*)p)[idx] != 0;
    case 1:  return ((const unsigned char*)p)[idx] != 0;
    case 2:  return ((const unsigned short*)p)[idx] != 0;
    default: return ((const unsigned int*)p)[idx] != 0;
  }
}

// ============ init: detect mask dtype + float width ============
__global__ void k_init(const void* __restrict__ mask_p, const void* __restrict__ h0_p,
                       unsigned char* __restrict__ ws) {
  int tid = threadIdx.x;
  __shared__ int s_b1, s_bf, s_f32, s_votes;
  if (tid == 0) { s_b1 = 0; s_bf = 0; s_f32 = 0; s_votes = 0; }
  __syncthreads();
  int b1 = 0, bfh = 0, f32h = 0;
  const unsigned int* dv = (const unsigned int*)mask_p;
  for (int i = tid; i < 4096; i += 256) {
    unsigned int d = dv[i];
    if (((d >> 8) & 0xFFu) == 1u || ((d >> 16) & 0xFFu) == 1u || ((d >> 24) & 0xFFu) == 1u) b1 = 1;
    if ((d & 0xFFFFu) == 0x3F80u) bfh = 1;
    if (d == 0x3F800000u) f32h = 1;
  }
  if (b1)  atomicOr(&s_b1, 1);
  if (bfh) atomicOr(&s_bf, 1);
  if (f32h) atomicOr(&s_f32, 1);
  if (tid < 128) {
    unsigned int d = ((const unsigned int*)h0_p)[tid];
    int e = (int)((d >> 23) & 0xFF);
    if (e >= 100 && e <= 140) atomicAdd(&s_votes, 1);
  }
  __syncthreads();
  if (tid == 0) {
    int mode = s_b1 ? 1 : (s_bf ? 2 : (s_f32 ? 3 : 0));
    *(int*)(ws + OFF_MODE)  = mode;
    *(int*)(ws + OFF_FMODE) = (s_votes >= 64) ? 1 : 0;
  }
}

// ============ A = x@W + b ; Axa = x@Wa + ba  (bf16 out) ============
__global__ __launch_bounds__(256) void k_xgemm(
    const void* __restrict__ x, const void* __restrict__ W, const void* __restrict__ b,
    const void* __restrict__ Wa, const void* __restrict__ ba, unsigned char* __restrict__ ws) {
  const int fm = *(const int*)(ws + OFF_FMODE);
  bf16* A   = (bf16*)(ws + OFF_A);
  bf16* Axa = (bf16*)(ws + OFF_AXA);
  const int tid = threadIdx.x;
  const int t0 = blockIdx.x * 8;
  __shared__ float sx[8][128];
  {
    int flat = tid * 4, r = flat >> 7, k = flat & 127;
    ld4(x, (size_t)(t0 + r) * D_IN + k, fm, &sx[r][k]);
  }
  __syncthreads();
  const bool isA = (tid < 192);
  const int c0 = isA ? tid * 8 : (tid - 192) * 8;
  const void* M = isA ? W : Wa;
  const int ldm = isA ? G3 : H_DIM;
  float acc[8][8];
#pragma unroll
  for (int r = 0; r < 8; ++r)
#pragma unroll
    for (int c = 0; c < 8; ++c) acc[r][c] = 0.f;
  for (int k = 0; k < D_IN; ++k) {
    float wv[8];
    ld8(M, (size_t)k * ldm + c0, fm, wv);
#pragma unroll
    for (int r = 0; r < 8; ++r) {
      float xv = sx[r][k];
#pragma unroll
      for (int c = 0; c < 8; ++c) acc[r][c] += xv * wv[c];
    }
  }
  float bias[8];
  ld8(isA ? b : ba, c0, fm, bias);
#pragma unroll
  for (int r = 0; r < 8; ++r) {
    uint4 o;
    o.x = packbf(acc[r][0] + bias[0], acc[r][1] + bias[1]);
    o.y = packbf(acc[r][2] + bias[2], acc[r][3] + bias[3]);
    o.z = packbf(acc[r][4] + bias[4], acc[r][5] + bias[5]);
    o.w = packbf(acc[r][6] + bias[6], acc[r][7] + bias[7]);
    if (isA) *(uint4*)(A + (size_t)(t0 + r) * G3 + c0) = o;
    else     *(uint4*)(Axa + (size_t)(t0 + r) * H_DIM + c0) = o;
  }
}

// ============ GW0[row] = emb[wid]@Ww + bw  (masked rows only, bf16 out) ============
__global__ __launch_bounds__(256) void k_wgemm(
    const int* __restrict__ wids, const void* __restrict__ wmask,
    const void* __restrict__ emb, const void* __restrict__ Ww, const void* __restrict__ bw,
    unsigned char* __restrict__ ws) {
  const int mode = *(const int*)(ws + OFF_MODE);
  const int fm   = *(const int*)(ws + OFF_FMODE);
  bf16* GW0 = (bf16*)(ws + OFF_GW0);
  const int tid = threadIdx.x;
  const int r0 = blockIdx.x * 8;
  bool m[8]; bool any = false;
#pragma unroll
  for (int r = 0; r < 8; ++r) {
    bool mm = readmask(wmask, r0 + r, mode);
    m[r] = mm; any |= mm;
  }
  if (!any) return;
  __shared__ float se[8][E_DIM];
#pragma unroll
  for (int r = 0; r < 8; ++r)
    if (m[r]) {
      int wid = wids[r0 + r];
      se[r][tid] = ldf(emb, (size_t)wid * E_DIM + tid, fm);
    }
  __syncthreads();
  if (tid < 192) {
    const int c0 = tid * 8;
    float acc[8][8];
#pragma unroll
    for (int r = 0; r < 8; ++r)
#pragma unroll
      for (int c = 0; c < 8; ++c) acc[r][c] = 0.f;
    for (int k = 0; k < E_DIM; ++k) {
      float wv[8];
      ld8(Ww, (size_t)k * G3 + c0, fm, wv);
#pragma unroll
      for (int r = 0; r < 8; ++r)
        if (m[r]) {
          float xv = se[r][k];
#pragma unroll
          for (int c = 0; c < 8; ++c) acc[r][c] += xv * wv[c];
        }
    }
    float bias[8];
    ld8(bw, c0, fm, bias);
#pragma unroll
    for (int r = 0; r < 8; ++r)
      if (m[r]) {
        uint4 o;
        o.x = packbf(acc[r][0] + bias[0], acc[r][1] + bias[1]);
        o.y = packbf(acc[r][2] + bias[2], acc[r][3] + bias[3]);
        o.z = packbf(acc[r][4] + bias[4], acc[r][5] + bias[5]);
        o.w = packbf(acc[r][6] + bias[6], acc[r][7] + bias[7]);
        *(uint4*)(GW0 + (size_t)(r0 + r) * G3 + c0) = o;
      }
  }
}

// ---- per-wave dot pass: lane(cg=lane>>3, rg=lane&7); lane rows {64m+8rg..+7} ----
#define PASS(slotptr, wt, accvar) do {                                  \
    float _acc = 0.f;                                                   \
    const _Float16* _vp = (slotptr) + 8 * rg;                           \
    _Pragma("unroll")                                                   \
    for (int _m = 0; _m < 8; ++_m) {                                    \
      float4 _raw = *(const float4*)(_vp + 64 * _m);                    \
      half2v _h0 = __builtin_bit_cast(half2v, _raw.x);                  \
      half2v _h1 = __builtin_bit_cast(half2v, _raw.y);                  \
      half2v _h2 = __builtin_bit_cast(half2v, _raw.z);                  \
      half2v _h3 = __builtin_bit_cast(half2v, _raw.w);                  \
      _acc = fdot2(_h0, wt[_m * 4 + 0], _acc);                          \
      _acc = fdot2(_h1, wt[_m * 4 + 1], _acc);                          \
      _acc = fdot2(_h2, wt[_m * 4 + 2], _acc);                          \
      _acc = fdot2(_h3, wt[_m * 4 + 3], _acc);                          \
    }                                                                   \
    accvar = _acc;                                                      \
  } while (0)

// ============ sequential lattice recurrence: 64 persistent WGs, fence-free ============
__global__ __launch_bounds__(256, 1) void k_seq(
    const int* __restrict__ wstarts, const void* __restrict__ wmask,
    const void* __restrict__ h0_p, const void* __restrict__ c0_p,
    const void* __restrict__ U, const void* __restrict__ Uw, const void* __restrict__ Ua,
    unsigned char* __restrict__ ws, void* __restrict__ outp) {
  const int tid = threadIdx.x;
  const int blk = blockIdx.x;
  const int wv = tid >> 6;
  const int lane = tid & 63;
  const int cg = lane >> 3;
  const int rg = lane & 7;
  const int kbase = blk * 8 + wv * 2;  // global k for kl=0 of this wave

  const int mode = *(const int*)(ws + OFF_MODE);
  const int fm   = *(const int*)(ws + OFF_FMODE);
  const bf16* A   = (const bf16*)(ws + OFF_A);
  const bf16* Axa = (const bf16*)(ws + OFF_AXA);
  const bf16* GW0 = (const bf16*)(ws + OFF_GW0);
  unsigned int* HPK  = (unsigned int*)(ws + OFF_HPK);   // [8][512]
  unsigned int* CWPK = (unsigned int*)(ws + OFF_CWPK);  // [2][4][512]

  __shared__ __align__(16) _Float16 hring[8][520];    // full h ring (f16, +8 pad)
  __shared__ __align__(16) _Float16 cwlds[WNUM][520]; // full c_w per word (f16)
  __shared__ float cring[8][8];                       // own 8 c-columns ring (f32, local only)
  __shared__ float scr[4][8];                         // per-wave reduce scratch
  __shared__ float cwown[4][WNUM][2];                 // own c_w values per wave (f32)

  // ---- zero-init LDS (defense) ----
  {
    _Float16* hz = &hring[0][0];
    for (int i = tid; i < 8 * 520; i += 256) hz[i] = (_Float16)0.f;
    _Float16* cz = &cwlds[0][0];
    for (int i = tid; i < WNUM * 520; i += 256) cz[i] = (_Float16)0.f;
    if (tid < 64) (&cring[0][0])[tid] = 0.f;
    if (tid < 32) (&scr[0][0])[tid] = 0.f;
    if (tid < 32) (&cwown[0][0][0])[tid] = 0.f;
  }

  // ---- persistent weights in VGPRs (f16 pairs) ----
  half2v wU[32], wUw[32], wUa[32];
  {
    const int gate = cg >> 1;
    const int klw = cg & 1;
    const int colU = gate * H_DIM + (kbase + klw);  // valid when cg<6
    const int colA = kbase + cg;                    // valid when cg<2
#pragma unroll
    for (int mq = 0; mq < 32; ++mq) {
      int mm = mq >> 2, q = mq & 3;
      int r = 64 * mm + 8 * rg + 2 * q;
      float u0 = 0, u1 = 0, v0 = 0, v1 = 0, a0 = 0, a1 = 0;
      if (cg < 6) {
        u0 = ldf(U, (size_t)r * G3 + colU, fm);  u1 = ldf(U, (size_t)(r + 1) * G3 + colU, fm);
        v0 = ldf(Uw, (size_t)r * G3 + colU, fm); v1 = ldf(Uw, (size_t)(r + 1) * G3 + colU, fm);
      }
      if (cg < 2) {
        a0 = ldf(Ua, (size_t)r * H_DIM + colA, fm); a1 = ldf(Ua, (size_t)(r + 1) * H_DIM + colA, fm);
      }
      wU[mq] = make2(u0, u1); wUw[mq] = make2(v0, v1); wUa[mq] = make2(a0, a1);
    }
  }
  __syncthreads();

  // ---- preload ring slot 7 with h0/c0 (the "t-1" state of step 0) ----
  {
    int i = tid * 2;
    hring[7][i]     = (_Float16)ldf(h0_p, i, fm);
    hring[7][i + 1] = (_Float16)ldf(h0_p, i + 1, fm);
    if (tid < 8) cring[7][tid] = ldf(c0_p, blk * 8 + tid, fm);
  }
  __syncthreads();

  for (int t = 0; t < T_LEN; ++t) {
    // ---- word metadata + ALL per-step scalars issued unconditionally up front:
    //      every load below is independent (no mask->gwx dependency) and overlaps
    //      the h[t-1] poll. Unmasked GW0 rows hold poison but are never used.
    int st[WNUM]; bool val[WNUM]; bool anyw = false;
    float gwx[WNUM][6], aT[6], axaT[2];
#pragma unroll
    for (int w = 0; w < WNUM; ++w) {
      st[w] = wstarts[t * WNUM + w];
      bool mmk = readmask(wmask, t * WNUM + w, mode);
      val[w] = mmk; anyw |= mmk;
    }
#pragma unroll
    for (int w = 0; w < WNUM; ++w) {
#pragma unroll
      for (int g3 = 0; g3 < 3; ++g3) {
        // one dword = 2 bf16 (kbase is even)
        unsigned int u = *(const unsigned int*)(GW0 + (size_t)(t * WNUM + w) * G3 + g3 * H_DIM + kbase);
        gwx[w][g3 * 2]     = __builtin_bit_cast(float, u << 16);
        gwx[w][g3 * 2 + 1] = __builtin_bit_cast(float, u & 0xffff0000u);
      }
    }
#pragma unroll
    for (int g3 = 0; g3 < 3; ++g3) {
      unsigned int u = *(const unsigned int*)(A + (size_t)t * G3 + g3 * H_DIM + kbase);
      aT[g3 * 2]     = __builtin_bit_cast(float, u << 16);
      aT[g3 * 2 + 1] = __builtin_bit_cast(float, u & 0xffff0000u);
    }
    {
      unsigned int u = *(const unsigned int*)(Axa + (size_t)t * H_DIM + kbase);
      axaT[0] = __builtin_bit_cast(float, u << 16);
      axaT[1] = __builtin_bit_cast(float, u & 0xffff0000u);
    }

    // ---- P1: EARLY words (st <= t-2): compute c_w and publish before h-wait ----
    unsigned int* cwSlot = CWPK + (size_t)(t & 1) * WNUM * H_DIM;
#pragma unroll
    for (int w = 0; w < WNUM; ++w)
      if (val[w] && st[w] <= t - 2) {
        float accw;
        PASS(&hring[st[w] & 7][0], wUw, accw);
        float red = accw;
        red += __shfl_xor(red, 1); red += __shfl_xor(red, 2); red += __shfl_xor(red, 4);
        if (rg == 0 && cg < 6) scr[wv][cg] = red;
#pragma unroll
        for (int kl = 0; kl < 2; ++kl) {
          float f_ = scr[wv][0 + kl] + gwx[w][0 + kl];
          float i_ = scr[wv][2 + kl] + gwx[w][2 + kl];
          float g_ = scr[wv][4 + kl] + gwx[w][4 + kl];
          float cs = cring[st[w] & 7][wv * 2 + kl];
          float cw = sigm(f_) * cs + sigm(i_) * tanhfast(g_);
          if (lane == 0) {
            cwown[wv][w][kl] = cw;
            astore(cwSlot + w * H_DIM + kbase + kl, pack16(cw, t + 1));
          }
        }
      }

    // ---- W1: poll h[t-1] (self-validating packed words), sleep backoff ----
    if (t > 0) {
      const unsigned int expect = (unsigned int)t;   // tag of h[t-1]
      const unsigned int* hp = HPK + (size_t)((t - 1) & 7) * H_DIM + tid * 2;
      unsigned int v0 = aload(hp);
      unsigned int v1 = aload(hp + 1);
      while ((v0 >> 16) != expect || (v1 >> 16) != expect) {
        __builtin_amdgcn_s_sleep(2);
        v0 = aload(hp);
        v1 = aload(hp + 1);
      }
      int sl = (t - 1) & 7;
      hring[sl][tid * 2]     = unpack16(v0);
      hring[sl][tid * 2 + 1] = unpack16(v1);
    }
    __syncthreads();   // B1

    // ---- P2: LATE words (st == t-1): compute c_w and publish ----
#pragma unroll
    for (int w = 0; w < WNUM; ++w)
      if (val[w] && st[w] > t - 2) {
        float accw;
        PASS(&hring[(t - 1) & 7][0], wUw, accw);
        float red = accw;
        red += __shfl_xor(red, 1); red += __shfl_xor(red, 2); red += __shfl_xor(red, 4);
        if (rg == 0 && cg < 6) scr[wv][cg] = red;
#pragma unroll
        for (int kl = 0; kl < 2; ++kl) {
          float f_ = scr[wv][0 + kl] + gwx[w][0 + kl];
          float i_ = scr[wv][2 + kl] + gwx[w][2 + kl];
          float g_ = scr[wv][4 + kl] + gwx[w][4 + kl];
          float cs = cring[st[w] & 7][wv * 2 + kl];
          float cw = sigm(f_) * cs + sigm(i_) * tanhfast(g_);
          if (lane == 0) {
            cwown[wv][w][kl] = cw;
            astore(cwSlot + w * H_DIM + kbase + kl, pack16(cw, t + 1));
          }
        }
      }

    // ---- gates (overlaps c_w flight of other WGs) ----
    float ig[2], og[2], gg[2];
    {
      float accu;
      PASS(&hring[(t - 1) & 7][0], wU, accu);
      float red = accu;
      red += __shfl_xor(red, 1); red += __shfl_xor(red, 2); red += __shfl_xor(red, 4);
      if (rg == 0 && cg < 6) scr[wv][cg] = red;
#pragma unroll
      for (int kl = 0; kl < 2; ++kl) {
        ig[kl] = sigm(scr[wv][0 + kl] + aT[0 + kl]);
        og[kl] = sigm(scr[wv][2 + kl] + aT[2 + kl]);
        gg[kl] = tanhfast(scr[wv][4 + kl] + aT[4 + kl]);
      }
    }

    // ---- W2: poll c_w for valid words (sleep backoff), fill LDS ----
#pragma unroll
    for (int w = 0; w < WNUM; ++w)
      if (val[w]) {
        const unsigned int expect = (unsigned int)(t + 1);
        const unsigned int* cp = cwSlot + w * H_DIM + tid * 2;
        unsigned int v0 = aload(cp);
        unsigned int v1 = aload(cp + 1);
        while ((v0 >> 16) != expect || (v1 >> 16) != expect) {
          __builtin_amdgcn_s_sleep(2);
          v0 = aload(cp);
          v1 = aload(cp + 1);
        }
        cwlds[w][tid * 2]     = unpack16(v0);
        cwlds[w][tid * 2 + 1] = unpack16(v1);
      }
    __syncthreads();   // B2

    // ---- alpha = sigmoid(Axa + c_w @ Ua), own columns ----
    float aw[WNUM][2] = {{0.f,0.f},{0.f,0.f},{0.f,0.f},{0.f,0.f}};
#pragma unroll
    for (int w = 0; w < WNUM; ++w)
      if (val[w]) {
        float acca;
        PASS(&cwlds[w][0], wUa, acca);
        float red = acca;
        red += __shfl_xor(red, 1); red += __shfl_xor(red, 2); red += __shfl_xor(red, 4);
        if (rg == 0 && cg < 2) scr[wv][cg] = red;
        aw[w][0] = scr[wv][0]; aw[w][1] = scr[wv][1];
      }

    // ---- combine + publish h[t] ----
#pragma unroll
    for (int kl = 0; kl < 2; ++kl) {
      int kg = kbase + kl;
      float e0 = __expf(ig[kl]);
      float num = e0 * gg[kl], den = e0;
#pragma unroll
      for (int w = 0; w < WNUM; ++w)
        if (val[w]) {
          float al = sigm(aw[w][kl] + axaT[kl]);
          float ew = __expf(al);
          num += ew * cwown[wv][w][kl];
          den += ew;
        }
      float cprev = cring[(t - 1) & 7][wv * 2 + kl];
      float csoft = num / den;
      float cplain = (1.f - ig[kl]) * cprev + ig[kl] * gg[kl];
      float c1 = anyw ? csoft : cplain;
      float h1 = og[kl] * tanhfast(c1);
      if (lane == kl) {
        cring[t & 7][wv * 2 + kl] = c1;
        astore(HPK + (size_t)(t & 7) * H_DIM + kg, pack16(h1, t + 1));
        if (fm) {
          ((float*)outp)[(size_t)t * 1024 + kg] = h1;
          ((float*)outp)[(size_t)t * 1024 + 512 + kg] = c1;
        } else {
          ((bf16*)outp)[(size_t)t * 1024 + kg] = __float2bfloat16(h1);
          ((bf16*)outp)[(size_t)t * 1024 + 512 + kg] = __float2bfloat16(c1);
        }
      }
    }
  }
}

extern "C" void kernel_launch(void* const* d_in, const int* in_sizes, int n_in,
                              void* d_out, int out_size, void* d_ws, size_t ws_size,
                              hipStream_t stream) {
  const void* x    = d_in[0];
  const int* wids  = (const int*)d_in[1];
  const int* wst   = (const int*)d_in[2];
  const void* wmsk = d_in[3];
  const void* h0   = d_in[4];
  const void* c0   = d_in[5];
  const void* emb  = d_in[6];
  const void* W    = d_in[7];
  const void* U    = d_in[8];
  const void* b    = d_in[9];
  const void* Wa   = d_in[10];
  const void* Ua   = d_in[11];
  const void* ba   = d_in[12];
  const void* Ww   = d_in[13];
  const void* Uw   = d_in[14];
  const void* bw   = d_in[15];
  unsigned char* ws = (unsigned char*)d_ws;
  (void)in_sizes; (void)n_in; (void)out_size; (void)ws_size;

  k_init<<<1, 256, 0, stream>>>(wmsk, h0, ws);
  k_xgemm<<<512, 256, 0, stream>>>(x, W, b, Wa, ba, ws);
  k_wgemm<<<2048, 256, 0, stream>>>(wids, wmsk, emb, Ww, bw, ws);
  k_seq<<<NBLK, 256, 0, stream>>>(wst, wmsk, h0, c0, U, Uw, Ua, ws, d_out);
}